// Round 10
// baseline (385.938 us; speedup 1.0000x reference)
//
#include <hip/hip_runtime.h>
#include <hip/hip_bf16.h>

// EquivariantConvolution via bf16 MFMA — R9: R6 (passing, 58.1us) with ONE algebraic
// restructure: per-kk A-fragment build (h*tmp -> bf16, ~100 VALU/kk) replaced by
// constant A = bf16(tmp) and per-row f32 h-scaling of the MFMA output:
//   C[e,a] = sum_kk h[e,kk] * D_kk[e,a],  D_kk = mfma(ta, W_kk, 0).
// h-scale uses the PROVEN C-layout row mapping (row = lg*4 + r) and one aligned
// ds_read_b64 of 4 consecutive bf16 h-values per (kk,q). h applied in full f32.
// All staging / layouts / prologue / epilogue byte-identical to R6.
// GEMM view: C[e,a] = sum_{j,b} (h[e,j]*tmp[e,b]) * w2[j, a*32+b], K=1056 incl bias, N=32.

#define TPB 256
#define BM  256

typedef __attribute__((ext_vector_type(8))) short bf16x8;
typedef __attribute__((ext_vector_type(4))) float f32x4;

__device__ __forceinline__ ushort f2bf(float x) {
    __hip_bfloat16 b = __float2bfloat16(x);
    return __builtin_bit_cast(ushort, b);
}
__device__ __forceinline__ float bf2f_lo(unsigned int u) {
    return __builtin_bit_cast(float, u << 16);
}
__device__ __forceinline__ float bf2f_hi(unsigned int u) {
    return __builtin_bit_cast(float, u & 0xffff0000u);
}

__global__ __launch_bounds__(TPB, 3) void equiv_conv_mfma(
    const float* __restrict__ basis1,
    const float* __restrict__ basis2,
    const float* __restrict__ ef,
    const float* __restrict__ f,
    const int*   __restrict__ src_idx,
    const float* __restrict__ w1,
    const float* __restrict__ b1,
    const float* __restrict__ w2,
    const float* __restrict__ b2,
    float* __restrict__ out)
{
    // LDS: hT 16KB + shared region 16KB (tmpT then WL) = 32 KB.
    __shared__ ushort hT[32 * BM];        // [j][edge]  bf16 bits (intra-wave use)
    __shared__ ushort region[8192];       // first tmpT [g][edge][8], then WL [jr][g][a][i]

    ushort* tmpT = region;
    ushort* WL   = region;

    const int tid  = threadIdx.x;
    const int base = blockIdx.x * BM;
    const int e    = base + tid;

    const int jr = tid >> 5;      // row-in-chunk this thread stages
    const int tt = tid & 31;

    // ---- issue chunk-0 w2 loads early (land under prologue compute) ----
    f32x4 stg[8];
    {
        const float* p = w2 + jr * 1024 + tt * 4;
        #pragma unroll
        for (int i = 0; i < 8; ++i)
            stg[i] = *reinterpret_cast<const f32x4*>(p + i * 128);
    }

    // write staged regs (bf16) into WL; works for bias row too (jr==0).
    auto write_stage = [&]() {
        const int g   = (tt >> 1) & 3;
        const int i0v = (tt & 1) * 4;
        #pragma unroll
        for (int i = 0; i < 8; ++i) {
            const int a = i * 4 + (tt >> 3);
            unsigned int lo = (unsigned int)f2bf(stg[i][0]) | ((unsigned int)f2bf(stg[i][1]) << 16);
            unsigned int hi = (unsigned int)f2bf(stg[i][2]) | ((unsigned int)f2bf(stg[i][3]) << 16);
            *reinterpret_cast<uint2*>(&WL[jr * 1024 + g * 256 + a * 8 + i0v]) =
                make_uint2(lo, hi);
        }
    };

    // ---- prologue: h = relu(ef@w1 + b1) -> hT (bf16) ----
    {
        float efr[16];
        const f32x4* p4 = reinterpret_cast<const f32x4*>(ef + e * 16);
        #pragma unroll
        for (int i = 0; i < 4; ++i) {
            f32x4 v = p4[i];
            efr[i*4+0] = v[0]; efr[i*4+1] = v[1]; efr[i*4+2] = v[2]; efr[i*4+3] = v[3];
        }
        #pragma unroll
        for (int j = 0; j < 32; ++j) {
            float hv = b1[j];
            #pragma unroll
            for (int i = 0; i < 16; ++i)
                hv = fmaf(efr[i], w1[i * 32 + j], hv);
            hT[j * BM + tid] = f2bf(fmaxf(hv, 0.f));
        }
    }

    // ---- prologue: tmp[m*4+k] = sum_d f_src[m][d]*basis1[d][k] -> tmpT (bf16) ----
    {
        float fr[32];
        const int s = src_idx[e];
        const f32x4* p4 = reinterpret_cast<const f32x4*>(f + s * 32);
        #pragma unroll
        for (int i = 0; i < 8; ++i) {
            f32x4 v = p4[i];
            fr[i*4+0] = v[0]; fr[i*4+1] = v[1]; fr[i*4+2] = v[2]; fr[i*4+3] = v[3];
        }
        float bs1[16];
        const f32x4* q4 = reinterpret_cast<const f32x4*>(basis1 + e * 16);
        #pragma unroll
        for (int i = 0; i < 4; ++i) {
            f32x4 v = q4[i];
            bs1[i*4+0] = v[0]; bs1[i*4+1] = v[1]; bs1[i*4+2] = v[2]; bs1[i*4+3] = v[3];
        }
        float tmp[32];
        #pragma unroll
        for (int m = 0; m < 8; ++m) {
            #pragma unroll
            for (int k = 0; k < 4; ++k) {
                float v = 0.f;
                #pragma unroll
                for (int d = 0; d < 4; ++d)
                    v = fmaf(fr[m*4+d], bs1[d*4+k], v);
                tmp[m*4+k] = v;
            }
        }
        #pragma unroll
        for (int g = 0; g < 4; ++g) {
            uint4 pk;
            pk.x = (unsigned int)f2bf(tmp[g*8+0]) | ((unsigned int)f2bf(tmp[g*8+1]) << 16);
            pk.y = (unsigned int)f2bf(tmp[g*8+2]) | ((unsigned int)f2bf(tmp[g*8+3]) << 16);
            pk.z = (unsigned int)f2bf(tmp[g*8+4]) | ((unsigned int)f2bf(tmp[g*8+5]) << 16);
            pk.w = (unsigned int)f2bf(tmp[g*8+6]) | ((unsigned int)f2bf(tmp[g*8+7]) << 16);
            *reinterpret_cast<uint4*>(&tmpT[(g * BM + tid) * 8]) = pk;
        }
    }

    // ---- per-wave tile setup: read constant A-fragments BEFORE region reuse ----
    const int lane = tid & 63;
    const int wid  = tid >> 6;
    const int l15  = lane & 15;
    const int lg   = lane >> 4;            // K-group (b = lg*8 + i)

    bf16x8 ta[4];                          // A-frag = bf16(tmp), K-loop invariant
    #pragma unroll
    for (int q = 0; q < 4; ++q) {
        const int edge = wid * 64 + q * 16 + l15;
        ta[q] = *reinterpret_cast<const bf16x8*>(&tmpT[(lg * BM + edge) * 8]);
    }

    __syncthreads();                       // WAR: all waves done reading tmpT region
    write_stage();                         // chunk 0 -> WL (same region)
    __syncthreads();                       // WL ready

    f32x4 Cacc[4][2];
    #pragma unroll
    for (int q = 0; q < 4; ++q)
        #pragma unroll
        for (int t = 0; t < 2; ++t)
            Cacc[q][t] = (f32x4){0.f, 0.f, 0.f, 0.f};

    const f32x4 kZero = (f32x4){0.f, 0.f, 0.f, 0.f};

    // ---- K-loop: 4 chunks x 8 rows, single-buffered WL ----
    #pragma unroll 1
    for (int c = 0; c < 4; ++c) {
        // issue next chunk's global loads (write to LDS after compute + barrier)
        if (c < 3) {
            const float* p = w2 + ((c + 1) * 8 + jr) * 1024 + tt * 4;
            #pragma unroll
            for (int i = 0; i < 8; ++i)
                stg[i] = *reinterpret_cast<const f32x4*>(p + i * 128);
        } else if (tid < 32) {             // bias2 row (jr==0, tt==tid)
            const float* p = b2 + tt * 4;
            #pragma unroll
            for (int i = 0; i < 8; ++i)
                stg[i] = *reinterpret_cast<const f32x4*>(p + i * 128);
        }

        const ushort* Wb = WL;
        #pragma unroll
        for (int j8 = 0; j8 < 8; ++j8) {
            const int kk = c * 8 + j8;
            bf16x8 bf0 = *reinterpret_cast<const bf16x8*>(&Wb[j8 * 1024 + lg * 256 + l15 * 8]);
            bf16x8 bf1 = *reinterpret_cast<const bf16x8*>(&Wb[j8 * 1024 + lg * 256 + (16 + l15) * 8]);
            #pragma unroll
            for (int q = 0; q < 4; ++q) {
                // 4 consecutive bf16 h-values for C rows lg*4 + 0..3 of this q-tile
                const uint2 hu = *reinterpret_cast<const uint2*>(
                    &hT[kk * BM + wid * 64 + q * 16 + lg * 4]);
                f32x4 hv4;
                hv4[0] = bf2f_lo(hu.x); hv4[1] = bf2f_hi(hu.x);
                hv4[2] = bf2f_lo(hu.y); hv4[3] = bf2f_hi(hu.y);
                f32x4 d0 = __builtin_amdgcn_mfma_f32_16x16x32_bf16(ta[q], bf0, kZero, 0, 0, 0);
                f32x4 d1 = __builtin_amdgcn_mfma_f32_16x16x32_bf16(ta[q], bf1, kZero, 0, 0, 0);
                Cacc[q][0] += hv4 * d0;
                Cacc[q][1] += hv4 * d1;
            }
        }

        __syncthreads();                   // everyone done reading WL
        if (c < 3) write_stage();
        else if (tid < 32) write_stage();  // bias row into row 0
        __syncthreads();                   // WL ready for next chunk / bias step
    }

    // ---- bias2 K-step (implicit h == 1): C += mfma(ta, bias, 0) ----
    {
        bf16x8 bb0 = *reinterpret_cast<const bf16x8*>(&WL[lg * 256 + l15 * 8]);
        bf16x8 bb1 = *reinterpret_cast<const bf16x8*>(&WL[lg * 256 + (16 + l15) * 8]);
        #pragma unroll
        for (int q = 0; q < 4; ++q) {
            f32x4 d0 = __builtin_amdgcn_mfma_f32_16x16x32_bf16(ta[q], bb0, kZero, 0, 0, 0);
            f32x4 d1 = __builtin_amdgcn_mfma_f32_16x16x32_bf16(ta[q], bb1, kZero, 0, 0, 0);
            Cacc[q][0] += d0;
            Cacc[q][1] += d1;
        }
    }

    // ---- epilogue: out[e,m2,d2] = sum_k2 C[e, m2*4+k2] * basis2[e,k2,d2] ----
    // C layout (verified): col a = lane&15 (+16*t), row = (lane>>4)*4 + reg.
    const int k2  = lane & 3;
    const int m2l = (lane >> 2) & 3;
    #pragma unroll
    for (int q = 0; q < 4; ++q) {
        #pragma unroll
        for (int r = 0; r < 4; ++r) {
            const int eg = base + wid * 64 + q * 16 + lg * 4 + r;
            f32x4 bs2 = *reinterpret_cast<const f32x4*>(basis2 + eg * 16 + k2 * 4);
            #pragma unroll
            for (int t = 0; t < 2; ++t) {
                const float v = Cacc[q][t][r];
                float p0 = v * bs2[0], p1 = v * bs2[1], p2 = v * bs2[2], p3 = v * bs2[3];
                p0 += __shfl_xor(p0, 1); p0 += __shfl_xor(p0, 2);
                p1 += __shfl_xor(p1, 1); p1 += __shfl_xor(p1, 2);
                p2 += __shfl_xor(p2, 1); p2 += __shfl_xor(p2, 2);
                p3 += __shfl_xor(p3, 1); p3 += __shfl_xor(p3, 2);
                const float ov = (k2 == 0) ? p0 : (k2 == 1) ? p1 : (k2 == 2) ? p2 : p3;
                out[eg * 32 + (t * 4 + m2l) * 4 + k2] = ov;
            }
        }
    }
}

extern "C" void kernel_launch(void* const* d_in, const int* in_sizes, int n_in,
                              void* d_out, int out_size, void* d_ws, size_t ws_size,
                              hipStream_t stream) {
    const float* basis1 = (const float*)d_in[0];
    const float* basis2 = (const float*)d_in[1];
    const float* ef     = (const float*)d_in[2];
    const float* f      = (const float*)d_in[3];
    const int*   src    = (const int*)  d_in[4];
    const float* w1     = (const float*)d_in[5];
    const float* b1     = (const float*)d_in[6];
    const float* w2     = (const float*)d_in[7];
    const float* b2     = (const float*)d_in[8];
    float* out = (float*)d_out;

    const int E = in_sizes[4];            // 262144
    const int nblocks = E / BM;           // 1024

    equiv_conv_mfma<<<nblocks, TPB, 0, stream>>>(
        basis1, basis2, ef, f, src, w1, b1, w2, b2, out);
}

// Round 11
// 55.523 us; speedup vs baseline: 6.9510x; 6.9510x over previous
//
#include <hip/hip_runtime.h>
#include <hip/hip_bf16.h>

// EquivariantConvolution via bf16 MFMA — R10: exact R6 structure (passed, 58.1us)
// with ONE change: the per-kk A-fragment build uses truncation-to-bf16 packed by
// v_perm_b32 (1 inst per pair) instead of __float2bfloat16 software-RNE (~5 VALU/elem).
// R9 lesson: accumulator must remain an MFMA C-operand (post-MFMA VALU scaling spilled).
// GEMM view: C[e,a] = sum_{j,b} (h[e,j]*tmp[e,b]) * w2[j, a*32+b], K=1056 incl bias, N=32.

#define TPB 256
#define BM  256

typedef __attribute__((ext_vector_type(8))) short bf16x8;
typedef __attribute__((ext_vector_type(4))) float f32x4;
typedef __attribute__((ext_vector_type(4))) unsigned int u32x4;

__device__ __forceinline__ ushort f2bf(float x) {
    __hip_bfloat16 b = __float2bfloat16(x);
    return __builtin_bit_cast(ushort, b);
}
__device__ __forceinline__ float bf2f(ushort u) {
    unsigned int v = ((unsigned int)u) << 16;
    return __builtin_bit_cast(float, v);
}
// pack trunc-bf16(m0), trunc-bf16(m1) into one u32 (m0 -> low16, m1 -> high16)
__device__ __forceinline__ unsigned int pack_trunc(float m0, float m1) {
    return __builtin_amdgcn_perm(__builtin_bit_cast(unsigned int, m1),
                                 __builtin_bit_cast(unsigned int, m0),
                                 0x07060302u);
}

__global__ __launch_bounds__(TPB, 3) void equiv_conv_mfma(
    const float* __restrict__ basis1,
    const float* __restrict__ basis2,
    const float* __restrict__ ef,
    const float* __restrict__ f,
    const int*   __restrict__ src_idx,
    const float* __restrict__ w1,
    const float* __restrict__ b1,
    const float* __restrict__ w2,
    const float* __restrict__ b2,
    float* __restrict__ out)
{
    // LDS: hT 16KB + shared region 16KB (tmpT then WL) = 32 KB.
    __shared__ ushort hT[32 * BM];        // [j][edge]  bf16 bits (intra-wave use)
    __shared__ ushort region[8192];       // first tmpT [g][edge][8], then WL [jr][g][a][i]

    ushort* tmpT = region;
    ushort* WL   = region;

    const int tid  = threadIdx.x;
    const int base = blockIdx.x * BM;
    const int e    = base + tid;

    const int jr = tid >> 5;      // row-in-chunk this thread stages
    const int tt = tid & 31;

    // ---- issue chunk-0 w2 loads early (land under prologue compute) ----
    f32x4 stg[8];
    {
        const float* p = w2 + jr * 1024 + tt * 4;
        #pragma unroll
        for (int i = 0; i < 8; ++i)
            stg[i] = *reinterpret_cast<const f32x4*>(p + i * 128);
    }

    // write staged regs (bf16) into WL; works for bias row too (jr==0).
    auto write_stage = [&]() {
        const int g   = (tt >> 1) & 3;
        const int i0v = (tt & 1) * 4;
        #pragma unroll
        for (int i = 0; i < 8; ++i) {
            const int a = i * 4 + (tt >> 3);
            unsigned int lo = (unsigned int)f2bf(stg[i][0]) | ((unsigned int)f2bf(stg[i][1]) << 16);
            unsigned int hi = (unsigned int)f2bf(stg[i][2]) | ((unsigned int)f2bf(stg[i][3]) << 16);
            *reinterpret_cast<uint2*>(&WL[jr * 1024 + g * 256 + a * 8 + i0v]) =
                make_uint2(lo, hi);
        }
    };

    // ---- prologue: h = relu(ef@w1 + b1) -> hT (bf16) ----
    {
        float efr[16];
        const f32x4* p4 = reinterpret_cast<const f32x4*>(ef + e * 16);
        #pragma unroll
        for (int i = 0; i < 4; ++i) {
            f32x4 v = p4[i];
            efr[i*4+0] = v[0]; efr[i*4+1] = v[1]; efr[i*4+2] = v[2]; efr[i*4+3] = v[3];
        }
        #pragma unroll
        for (int j = 0; j < 32; ++j) {
            float hv = b1[j];
            #pragma unroll
            for (int i = 0; i < 16; ++i)
                hv = fmaf(efr[i], w1[i * 32 + j], hv);
            hT[j * BM + tid] = f2bf(fmaxf(hv, 0.f));
        }
    }

    // ---- prologue: tmp[m*4+k] = sum_d f_src[m][d]*basis1[d][k] -> tmpT (bf16) ----
    {
        float fr[32];
        const int s = src_idx[e];
        const f32x4* p4 = reinterpret_cast<const f32x4*>(f + s * 32);
        #pragma unroll
        for (int i = 0; i < 8; ++i) {
            f32x4 v = p4[i];
            fr[i*4+0] = v[0]; fr[i*4+1] = v[1]; fr[i*4+2] = v[2]; fr[i*4+3] = v[3];
        }
        float bs1[16];
        const f32x4* q4 = reinterpret_cast<const f32x4*>(basis1 + e * 16);
        #pragma unroll
        for (int i = 0; i < 4; ++i) {
            f32x4 v = q4[i];
            bs1[i*4+0] = v[0]; bs1[i*4+1] = v[1]; bs1[i*4+2] = v[2]; bs1[i*4+3] = v[3];
        }
        float tmp[32];
        #pragma unroll
        for (int m = 0; m < 8; ++m) {
            #pragma unroll
            for (int k = 0; k < 4; ++k) {
                float v = 0.f;
                #pragma unroll
                for (int d = 0; d < 4; ++d)
                    v = fmaf(fr[m*4+d], bs1[d*4+k], v);
                tmp[m*4+k] = v;
            }
        }
        #pragma unroll
        for (int g = 0; g < 4; ++g) {
            uint4 pk;
            pk.x = (unsigned int)f2bf(tmp[g*8+0]) | ((unsigned int)f2bf(tmp[g*8+1]) << 16);
            pk.y = (unsigned int)f2bf(tmp[g*8+2]) | ((unsigned int)f2bf(tmp[g*8+3]) << 16);
            pk.z = (unsigned int)f2bf(tmp[g*8+4]) | ((unsigned int)f2bf(tmp[g*8+5]) << 16);
            pk.w = (unsigned int)f2bf(tmp[g*8+6]) | ((unsigned int)f2bf(tmp[g*8+7]) << 16);
            *reinterpret_cast<uint4*>(&tmpT[(g * BM + tid) * 8]) = pk;
        }
    }

    // ---- per-wave tile setup: read tmpf BEFORE region is reused as WL ----
    const int lane = tid & 63;
    const int wid  = tid >> 6;
    const int l15  = lane & 15;
    const int lg   = lane >> 4;            // K-group (b = lg*8 + i)

    float tmpf[4][8];                      // per-tile tmp[b] as f32, K-loop invariant
    #pragma unroll
    for (int q = 0; q < 4; ++q) {
        const int edge = wid * 64 + q * 16 + l15;
        bf16x8 tv = *reinterpret_cast<const bf16x8*>(&tmpT[(lg * BM + edge) * 8]);
        #pragma unroll
        for (int i = 0; i < 8; ++i) tmpf[q][i] = bf2f((ushort)tv[i]);
    }

    __syncthreads();                       // WAR: all waves done reading tmpT region
    write_stage();                         // chunk 0 -> WL (same region)
    __syncthreads();                       // WL ready

    f32x4 acc[4][2];
    #pragma unroll
    for (int q = 0; q < 4; ++q) {
        #pragma unroll
        for (int t = 0; t < 2; ++t) {
            acc[q][t][0] = 0.f; acc[q][t][1] = 0.f; acc[q][t][2] = 0.f; acc[q][t][3] = 0.f;
        }
    }

    // ---- K-loop: 4 chunks x 8 rows, single-buffered WL ----
    #pragma unroll 1
    for (int c = 0; c < 4; ++c) {
        // issue next chunk's global loads (write to LDS after compute + barrier)
        if (c < 3) {
            const float* p = w2 + ((c + 1) * 8 + jr) * 1024 + tt * 4;
            #pragma unroll
            for (int i = 0; i < 8; ++i)
                stg[i] = *reinterpret_cast<const f32x4*>(p + i * 128);
        } else if (tid < 32) {             // bias2 row (jr==0, tt==tid)
            const float* p = b2 + tt * 4;
            #pragma unroll
            for (int i = 0; i < 8; ++i)
                stg[i] = *reinterpret_cast<const f32x4*>(p + i * 128);
        }

        const ushort* Wb = WL;
        #pragma unroll
        for (int j8 = 0; j8 < 8; ++j8) {
            const int kk = c * 8 + j8;
            bf16x8 bf0 = *reinterpret_cast<const bf16x8*>(&Wb[j8 * 1024 + lg * 256 + l15 * 8]);
            bf16x8 bf1 = *reinterpret_cast<const bf16x8*>(&Wb[j8 * 1024 + lg * 256 + (16 + l15) * 8]);
            #pragma unroll
            for (int q = 0; q < 4; ++q) {
                const float hv = bf2f(hT[kk * BM + wid * 64 + q * 16 + l15]);
                u32x4 w;
                #pragma unroll
                for (int i = 0; i < 4; ++i)
                    w[i] = pack_trunc(hv * tmpf[q][2*i], hv * tmpf[q][2*i+1]);
                const bf16x8 af = __builtin_bit_cast(bf16x8, w);
                acc[q][0] = __builtin_amdgcn_mfma_f32_16x16x32_bf16(af, bf0, acc[q][0], 0, 0, 0);
                acc[q][1] = __builtin_amdgcn_mfma_f32_16x16x32_bf16(af, bf1, acc[q][1], 0, 0, 0);
            }
        }

        __syncthreads();                   // everyone done reading WL
        if (c < 3) write_stage();
        else if (tid < 32) write_stage();  // bias row into row 0
        __syncthreads();                   // WL ready for next chunk / bias step
    }

    // ---- bias2 K-step (implicit h == 1, A = trunc(tmpf) == original bf16 bits) ----
    {
        bf16x8 bb0 = *reinterpret_cast<const bf16x8*>(&WL[lg * 256 + l15 * 8]);
        bf16x8 bb1 = *reinterpret_cast<const bf16x8*>(&WL[lg * 256 + (16 + l15) * 8]);
        #pragma unroll
        for (int q = 0; q < 4; ++q) {
            u32x4 w;
            #pragma unroll
            for (int i = 0; i < 4; ++i)
                w[i] = pack_trunc(tmpf[q][2*i], tmpf[q][2*i+1]);   // exact (values are bf16)
            const bf16x8 af = __builtin_bit_cast(bf16x8, w);
            acc[q][0] = __builtin_amdgcn_mfma_f32_16x16x32_bf16(af, bb0, acc[q][0], 0, 0, 0);
            acc[q][1] = __builtin_amdgcn_mfma_f32_16x16x32_bf16(af, bb1, acc[q][1], 0, 0, 0);
        }
    }

    // ---- epilogue: out[e,m2,d2] = sum_k2 C[e, m2*4+k2] * basis2[e,k2,d2] ----
    // C layout (verified): col a = lane&15 (+16*t), row = (lane>>4)*4 + reg.
    const int k2  = lane & 3;
    const int m2l = (lane >> 2) & 3;
    #pragma unroll
    for (int q = 0; q < 4; ++q) {
        #pragma unroll
        for (int r = 0; r < 4; ++r) {
            const int eg = base + wid * 64 + q * 16 + lg * 4 + r;
            f32x4 bs2 = *reinterpret_cast<const f32x4*>(basis2 + eg * 16 + k2 * 4);
            #pragma unroll
            for (int t = 0; t < 2; ++t) {
                const float v = acc[q][t][r];
                float p0 = v * bs2[0], p1 = v * bs2[1], p2 = v * bs2[2], p3 = v * bs2[3];
                p0 += __shfl_xor(p0, 1); p0 += __shfl_xor(p0, 2);
                p1 += __shfl_xor(p1, 1); p1 += __shfl_xor(p1, 2);
                p2 += __shfl_xor(p2, 1); p2 += __shfl_xor(p2, 2);
                p3 += __shfl_xor(p3, 1); p3 += __shfl_xor(p3, 2);
                const float ov = (k2 == 0) ? p0 : (k2 == 1) ? p1 : (k2 == 2) ? p2 : p3;
                out[eg * 32 + (t * 4 + m2l) * 4 + k2] = ov;
            }
        }
    }
}

extern "C" void kernel_launch(void* const* d_in, const int* in_sizes, int n_in,
                              void* d_out, int out_size, void* d_ws, size_t ws_size,
                              hipStream_t stream) {
    const float* basis1 = (const float*)d_in[0];
    const float* basis2 = (const float*)d_in[1];
    const float* ef     = (const float*)d_in[2];
    const float* f      = (const float*)d_in[3];
    const int*   src    = (const int*)  d_in[4];
    const float* w1     = (const float*)d_in[5];
    const float* b1     = (const float*)d_in[6];
    const float* w2     = (const float*)d_in[7];
    const float* b2     = (const float*)d_in[8];
    float* out = (float*)d_out;

    const int E = in_sizes[4];            // 262144
    const int nblocks = E / BM;           // 1024

    equiv_conv_mfma<<<nblocks, TPB, 0, stream>>>(
        basis1, basis2, ef, f, src, w1, b1, w2, b2, out);
}

// Round 12
// 48.015 us; speedup vs baseline: 8.0379x; 1.1564x over previous
//
#include <hip/hip_runtime.h>
#include <hip/hip_bf16.h>

// EquivariantConvolution via bf16 MFMA — R11: R10 (passed, 55.5us) with the work
// repartitioned for TLP: TPB 256 -> 512 (8 waves/block), each wave computes 32 edges
// (q in {0,1}); BM=256 and ALL layouts (hT/tmpT/WL/C-frag/epilogue) unchanged.
// R10 post-mortem: latency-bound at 4 waves/SIMD (VALU 35%, MFMA 10%, HBM 14%) —
// lever is resident waves, not fewer ops. Staging re-derived for 512 threads:
// col = tt2*4 + i*256 -> a = i*8 + (tt2>>3), g = (tt2>>1)&3, i0 = (tt2&1)*4.
// tmpT is now cross-wave -> added one barrier after the prologue.
// GEMM view: C[e,a] = sum_{j,b} (h[e,j]*tmp[e,b]) * w2[j, a*32+b], K=1056 incl bias, N=32.

#define TPB 512
#define BM  256

typedef __attribute__((ext_vector_type(8))) short bf16x8;
typedef __attribute__((ext_vector_type(4))) float f32x4;
typedef __attribute__((ext_vector_type(4))) unsigned int u32x4;

__device__ __forceinline__ ushort f2bf(float x) {
    __hip_bfloat16 b = __float2bfloat16(x);
    return __builtin_bit_cast(ushort, b);
}
__device__ __forceinline__ float bf2f(ushort u) {
    unsigned int v = ((unsigned int)u) << 16;
    return __builtin_bit_cast(float, v);
}
// pack trunc-bf16(m0), trunc-bf16(m1) into one u32 (m0 -> low16, m1 -> high16)
__device__ __forceinline__ unsigned int pack_trunc(float m0, float m1) {
    return __builtin_amdgcn_perm(__builtin_bit_cast(unsigned int, m1),
                                 __builtin_bit_cast(unsigned int, m0),
                                 0x07060302u);
}

__global__ __launch_bounds__(TPB, 6) void equiv_conv_mfma(
    const float* __restrict__ basis1,
    const float* __restrict__ basis2,
    const float* __restrict__ ef,
    const float* __restrict__ f,
    const int*   __restrict__ src_idx,
    const float* __restrict__ w1,
    const float* __restrict__ b1,
    const float* __restrict__ w2,
    const float* __restrict__ b2,
    float* __restrict__ out)
{
    // LDS: hT 16KB + shared region 16KB (tmpT then WL) = 32 KB.
    __shared__ ushort hT[32 * BM];        // [j][edge]  bf16 bits
    __shared__ ushort region[8192];       // first tmpT [g][edge][8], then WL [jr][g][a][i]

    ushort* tmpT = region;
    ushort* WL   = region;

    const int tid  = threadIdx.x;
    const int base = blockIdx.x * BM;

    const int jr2 = tid >> 6;     // row-in-chunk this thread stages (0..7)
    const int tt2 = tid & 63;

    // ---- issue chunk-0 w2 loads early (land under prologue compute) ----
    // thread covers row jr2, cols tt2*4 + i*256 + (0..3), i = 0..3
    f32x4 stg[4];
    {
        const float* p = w2 + jr2 * 1024 + tt2 * 4;
        #pragma unroll
        for (int i = 0; i < 4; ++i)
            stg[i] = *reinterpret_cast<const f32x4*>(p + i * 256);
    }

    // write staged regs (bf16) into WL; col = tt2*4 + i*256 + l:
    //   a = i*8 + (tt2>>3), b = (tt2&7)*4 + l -> g = (tt2>>1)&3, i0 = (tt2&1)*4.
    auto write_stage = [&]() {
        const int g   = (tt2 >> 1) & 3;
        const int i0v = (tt2 & 1) * 4;
        #pragma unroll
        for (int i = 0; i < 4; ++i) {
            const int a = i * 8 + (tt2 >> 3);
            unsigned int lo = (unsigned int)f2bf(stg[i][0]) | ((unsigned int)f2bf(stg[i][1]) << 16);
            unsigned int hi = (unsigned int)f2bf(stg[i][2]) | ((unsigned int)f2bf(stg[i][3]) << 16);
            *reinterpret_cast<uint2*>(&WL[jr2 * 1024 + g * 256 + a * 8 + i0v]) =
                make_uint2(lo, hi);
        }
    };

    // ---- prologue (edges are owned by threads 0..255) ----
    if (tid < BM) {
        const int e = base + tid;
        // h = relu(ef@w1 + b1) -> hT (bf16)
        {
            float efr[16];
            const f32x4* p4 = reinterpret_cast<const f32x4*>(ef + e * 16);
            #pragma unroll
            for (int i = 0; i < 4; ++i) {
                f32x4 v = p4[i];
                efr[i*4+0] = v[0]; efr[i*4+1] = v[1]; efr[i*4+2] = v[2]; efr[i*4+3] = v[3];
            }
            #pragma unroll
            for (int j = 0; j < 32; ++j) {
                float hv = b1[j];
                #pragma unroll
                for (int i = 0; i < 16; ++i)
                    hv = fmaf(efr[i], w1[i * 32 + j], hv);
                hT[j * BM + tid] = f2bf(fmaxf(hv, 0.f));
            }
        }
        // tmp[m*4+k] = sum_d f_src[m][d]*basis1[d][k] -> tmpT (bf16)
        {
            float fr[32];
            const int s = src_idx[e];
            const f32x4* p4 = reinterpret_cast<const f32x4*>(f + s * 32);
            #pragma unroll
            for (int i = 0; i < 8; ++i) {
                f32x4 v = p4[i];
                fr[i*4+0] = v[0]; fr[i*4+1] = v[1]; fr[i*4+2] = v[2]; fr[i*4+3] = v[3];
            }
            float bs1[16];
            const f32x4* q4 = reinterpret_cast<const f32x4*>(basis1 + e * 16);
            #pragma unroll
            for (int i = 0; i < 4; ++i) {
                f32x4 v = q4[i];
                bs1[i*4+0] = v[0]; bs1[i*4+1] = v[1]; bs1[i*4+2] = v[2]; bs1[i*4+3] = v[3];
            }
            float tmp[32];
            #pragma unroll
            for (int m = 0; m < 8; ++m) {
                #pragma unroll
                for (int k = 0; k < 4; ++k) {
                    float v = 0.f;
                    #pragma unroll
                    for (int d = 0; d < 4; ++d)
                        v = fmaf(fr[m*4+d], bs1[d*4+k], v);
                    tmp[m*4+k] = v;
                }
            }
            #pragma unroll
            for (int g = 0; g < 4; ++g) {
                uint4 pk;
                pk.x = (unsigned int)f2bf(tmp[g*8+0]) | ((unsigned int)f2bf(tmp[g*8+1]) << 16);
                pk.y = (unsigned int)f2bf(tmp[g*8+2]) | ((unsigned int)f2bf(tmp[g*8+3]) << 16);
                pk.z = (unsigned int)f2bf(tmp[g*8+4]) | ((unsigned int)f2bf(tmp[g*8+5]) << 16);
                pk.w = (unsigned int)f2bf(tmp[g*8+6]) | ((unsigned int)f2bf(tmp[g*8+7]) << 16);
                *reinterpret_cast<uint4*>(&tmpT[(g * BM + tid) * 8]) = pk;
            }
        }
    }

    __syncthreads();                       // tmpT/hT visible to all 8 waves

    // ---- per-wave tile setup: read tmpf BEFORE region is reused as WL ----
    const int lane = tid & 63;
    const int wid  = tid >> 6;             // 0..7, owns edges wid*32 .. wid*32+31
    const int l15  = lane & 15;
    const int lg   = lane >> 4;            // K-group (b = lg*8 + i)

    float tmpf[2][8];                      // per-tile tmp[b] as f32, K-loop invariant
    #pragma unroll
    for (int q = 0; q < 2; ++q) {
        const int edge = wid * 32 + q * 16 + l15;
        bf16x8 tv = *reinterpret_cast<const bf16x8*>(&tmpT[(lg * BM + edge) * 8]);
        #pragma unroll
        for (int i = 0; i < 8; ++i) tmpf[q][i] = bf2f((ushort)tv[i]);
    }

    __syncthreads();                       // WAR: all waves done reading tmpT region
    write_stage();                         // chunk 0 -> WL (same region)
    __syncthreads();                       // WL ready

    f32x4 acc[2][2];
    #pragma unroll
    for (int q = 0; q < 2; ++q) {
        #pragma unroll
        for (int t = 0; t < 2; ++t) {
            acc[q][t][0] = 0.f; acc[q][t][1] = 0.f; acc[q][t][2] = 0.f; acc[q][t][3] = 0.f;
        }
    }

    // ---- K-loop: 4 chunks x 8 rows, single-buffered WL ----
    #pragma unroll 1
    for (int c = 0; c < 4; ++c) {
        // issue next chunk's global loads (write to LDS after compute + barrier)
        if (c < 3) {
            const float* p = w2 + ((c + 1) * 8 + jr2) * 1024 + tt2 * 4;
            #pragma unroll
            for (int i = 0; i < 4; ++i)
                stg[i] = *reinterpret_cast<const f32x4*>(p + i * 256);
        } else if (tid < 64) {             // bias2 row (jr2==0, tt2==tid)
            const float* p = b2 + tt2 * 4;
            #pragma unroll
            for (int i = 0; i < 4; ++i)
                stg[i] = *reinterpret_cast<const f32x4*>(p + i * 256);
        }

        const ushort* Wb = WL;
        #pragma unroll
        for (int j8 = 0; j8 < 8; ++j8) {
            const int kk = c * 8 + j8;
            bf16x8 bf0 = *reinterpret_cast<const bf16x8*>(&Wb[j8 * 1024 + lg * 256 + l15 * 8]);
            bf16x8 bf1 = *reinterpret_cast<const bf16x8*>(&Wb[j8 * 1024 + lg * 256 + (16 + l15) * 8]);
            #pragma unroll
            for (int q = 0; q < 2; ++q) {
                const float hv = bf2f(hT[kk * BM + wid * 32 + q * 16 + l15]);
                u32x4 w;
                #pragma unroll
                for (int i = 0; i < 4; ++i)
                    w[i] = pack_trunc(hv * tmpf[q][2*i], hv * tmpf[q][2*i+1]);
                const bf16x8 af = __builtin_bit_cast(bf16x8, w);
                acc[q][0] = __builtin_amdgcn_mfma_f32_16x16x32_bf16(af, bf0, acc[q][0], 0, 0, 0);
                acc[q][1] = __builtin_amdgcn_mfma_f32_16x16x32_bf16(af, bf1, acc[q][1], 0, 0, 0);
            }
        }

        __syncthreads();                   // everyone done reading WL
        if (c < 3) write_stage();
        else if (tid < 64) write_stage();  // bias row into row 0
        __syncthreads();                   // WL ready for next chunk / bias step
    }

    // ---- bias2 K-step (implicit h == 1, A = trunc(tmpf) == original bf16 bits) ----
    {
        bf16x8 bb0 = *reinterpret_cast<const bf16x8*>(&WL[lg * 256 + l15 * 8]);
        bf16x8 bb1 = *reinterpret_cast<const bf16x8*>(&WL[lg * 256 + (16 + l15) * 8]);
        #pragma unroll
        for (int q = 0; q < 2; ++q) {
            u32x4 w;
            #pragma unroll
            for (int i = 0; i < 4; ++i)
                w[i] = pack_trunc(tmpf[q][2*i], tmpf[q][2*i+1]);   // exact (values are bf16)
            const bf16x8 af = __builtin_bit_cast(bf16x8, w);
            acc[q][0] = __builtin_amdgcn_mfma_f32_16x16x32_bf16(af, bb0, acc[q][0], 0, 0, 0);
            acc[q][1] = __builtin_amdgcn_mfma_f32_16x16x32_bf16(af, bb1, acc[q][1], 0, 0, 0);
        }
    }

    // ---- epilogue: out[e,m2,d2] = sum_k2 C[e, m2*4+k2] * basis2[e,k2,d2] ----
    // C layout (verified): col a = lane&15 (+16*t), row = (lane>>4)*4 + reg.
    const int k2  = lane & 3;
    const int m2l = (lane >> 2) & 3;
    #pragma unroll
    for (int q = 0; q < 2; ++q) {
        #pragma unroll
        for (int r = 0; r < 4; ++r) {
            const int eg = base + wid * 32 + q * 16 + lg * 4 + r;
            f32x4 bs2 = *reinterpret_cast<const f32x4*>(basis2 + eg * 16 + k2 * 4);
            #pragma unroll
            for (int t = 0; t < 2; ++t) {
                const float v = acc[q][t][r];
                float p0 = v * bs2[0], p1 = v * bs2[1], p2 = v * bs2[2], p3 = v * bs2[3];
                p0 += __shfl_xor(p0, 1); p0 += __shfl_xor(p0, 2);
                p1 += __shfl_xor(p1, 1); p1 += __shfl_xor(p1, 2);
                p2 += __shfl_xor(p2, 1); p2 += __shfl_xor(p2, 2);
                p3 += __shfl_xor(p3, 1); p3 += __shfl_xor(p3, 2);
                const float ov = (k2 == 0) ? p0 : (k2 == 1) ? p1 : (k2 == 2) ? p2 : p3;
                out[eg * 32 + (t * 4 + m2l) * 4 + k2] = ov;
            }
        }
    }
}

extern "C" void kernel_launch(void* const* d_in, const int* in_sizes, int n_in,
                              void* d_out, int out_size, void* d_ws, size_t ws_size,
                              hipStream_t stream) {
    const float* basis1 = (const float*)d_in[0];
    const float* basis2 = (const float*)d_in[1];
    const float* ef     = (const float*)d_in[2];
    const float* f      = (const float*)d_in[3];
    const int*   src    = (const int*)  d_in[4];
    const float* w1     = (const float*)d_in[5];
    const float* b1     = (const float*)d_in[6];
    const float* w2     = (const float*)d_in[7];
    const float* b2     = (const float*)d_in[8];
    float* out = (float*)d_out;

    const int E = in_sizes[4];            // 262144
    const int nblocks = E / BM;           // 1024

    equiv_conv_mfma<<<nblocks, TPB, 0, stream>>>(
        basis1, basis2, ef, f, src, w1, b1, w2, b2, out);
}